// Round 4
// baseline (525.265 us; speedup 1.0000x reference)
//
#include <hip/hip_runtime.h>
#include <math.h>

namespace {
constexpr int kB    = 32;
constexpr int kMel  = 128;
constexpr int kT    = 8192;
constexpr int kKeys = 88;
constexpr int kTop  = 15;   // top[13] = 14th largest, top[14] = 15th largest

// key_bins is DETERMINISTIC (no RNG): derived from the mel formula in the
// reference. Verified at runtime against d_in[1]; mismatch -> generic path.
__device__ constexpr int kBins[kKeys] = {
   1,  1,  1,  1,  1,  2,  2,  2,  2,  2,  2,  2,  2,  2,  3,  3,
   3,  3,  3,  3,  4,  4,  4,  4,  5,  5,  5,  6,  6,  6,  7,  7,
   7,  8,  8,  9,  9, 10, 10, 11, 12, 12, 13, 14, 15, 16, 17, 17,
  19, 20, 21, 22, 23, 25, 26, 28, 29, 31, 33, 35, 37, 39, 42, 44,
  46, 49, 51, 53, 56, 58, 60, 63, 65, 68, 70, 72, 75, 77, 79, 82,
  84, 86, 89, 91, 93, 96, 98, 101};
}

__device__ __forceinline__ void top_insert(float (&top)[kTop], float v) {
#pragma unroll
  for (int j = 0; j < kTop; ++j) {
    const float hi = fmaxf(top[j], v);
    v = fminf(top[j], v);
    top[j] = hi;
  }
}

__global__ __launch_bounds__(256, 4) void key_probs_kernel(
    const float* __restrict__ mel, const int* __restrict__ key_bins,
    float* __restrict__ out) {
  __shared__ int sbins[kKeys];
  __shared__ int smismatch;
  const int tid = threadIdx.x;
  if (tid == 0) smismatch = 0;
  __syncthreads();
  if (tid < kKeys) {
    const int m = key_bins[tid];
    sbins[tid] = m;
    if (m != kBins[tid]) atomicOr(&smismatch, 1);
  }
  __syncthreads();
  const bool generic = (smismatch != 0);

  const int t = blockIdx.x * 256 + tid;
  const int b = blockIdx.y;
  const float* mb = mel + (size_t)b * (kMel * kT);
  float* o0 = out + (size_t)b * kKeys * kT + t;
  float* o1 = o0 + (size_t)kB * kKeys * kT;

  // ---- phase A: streaming top-15 on log-domain sums (compile-time bins) ----
  // e = exp(a)exp(b)exp(c) is monotone in s = a+b+c; rank entirely in sums.
  float top[kTop];
#pragma unroll
  for (int j = 0; j < kTop; ++j) top[j] = -1e30f;
  if (!generic) {
#pragma unroll
    for (int k = 0; k < kKeys; ++k) {
      const int m = kBins[k];                    // compile-time constant
      float v = mb[(size_t)m * kT + t];
      if (m < 64) v += mb[(size_t)(2 * m) * kT + t];   // resolved at compile time
      if (m < 43) v += mb[(size_t)(3 * m) * kT + t];
      top_insert(top, v);
    }
  }

  const float r74 = top[13];
  // Only the rank-14/15 boundary gap matters; sum-space gap < ~2.5e-6 is
  // where the reference's product-space rounding could flip the boundary.
  const bool amb = generic || ((top[13] - top[14]) < 1e-5f);

  if (amb) {
    // COLD path (rare lanes / bins-mismatch): product space, runtime bins,
    // np-compatible correctly-rounded fp32 exp. Rolled -> tiny code footprint.
    float tp[kTop];
#pragma unroll
    for (int j = 0; j < kTop; ++j) tp[j] = 0.0f;   // products are positive
#pragma unroll 1
    for (int k = 0; k < kKeys; ++k) {
      const int m = __builtin_amdgcn_readfirstlane(sbins[k]);
      float v = (float)::exp((double)mb[(size_t)m * kT + t]);
      if (m < 64) v *= (float)::exp((double)mb[(size_t)(2 * m) * kT + t]);
      if (m < 43) v *= (float)::exp((double)mb[(size_t)(3 * m) * kT + t]);
      top_insert(tp, v);
    }
    const float r74p = tp[13];
#pragma unroll 1
    for (int k = 0; k < kKeys; ++k) {
      const int m = __builtin_amdgcn_readfirstlane(sbins[k]);
      float v = (float)::exp((double)mb[(size_t)m * kT + t]);
      if (m < 64) v *= (float)::exp((double)mb[(size_t)(2 * m) * kT + t]);
      if (m < 43) v *= (float)::exp((double)mb[(size_t)(3 * m) * kT + t]);
      const float r = (v >= r74p) ? 1.0f : 0.0f;
      o0[(size_t)k * kT] = r;
      o1[(size_t)k * kT] = r;
    }
  } else {
    // HOT path: recompute sums (same expression -> bit-identical), classify,
    // nontemporal stores keep mel resident in L3 for these re-reads.
#pragma unroll
    for (int k = 0; k < kKeys; ++k) {
      const int m = kBins[k];
      float v = mb[(size_t)m * kT + t];
      if (m < 64) v += mb[(size_t)(2 * m) * kT + t];
      if (m < 43) v += mb[(size_t)(3 * m) * kT + t];
      const float r = (v >= r74) ? 1.0f : 0.0f;
      __builtin_nontemporal_store(r, &o0[(size_t)k * kT]);
      __builtin_nontemporal_store(r, &o1[(size_t)k * kT]);
    }
  }
}

extern "C" void kernel_launch(void* const* d_in, const int* in_sizes, int n_in,
                              void* d_out, int out_size, void* d_ws, size_t ws_size,
                              hipStream_t stream) {
  const float* mel = (const float*)d_in[0];
  const int* key_bins = (const int*)d_in[1];
  float* out = (float*)d_out;
  dim3 grid(kT / 256, kB);
  key_probs_kernel<<<grid, dim3(256), 0, stream>>>(mel, key_bins, out);
}